// Round 5
// baseline (320.649 us; speedup 1.0000x reference)
//
#include <hip/hip_runtime.h>
#include <hip/hip_bf16.h>
#include <stdint.h>

#define SEQ 4096
#define DH  64
#define KT  32                 // keys per iteration per wave
#define PS  40                 // sP row stride in ushorts (80 B)
#define NIT ((SEQ / 2) / KT)   // 64 iters per wave (split-K halves)
#define QSCALE 0.090168440f    // log2(e)/16 folded into Q

typedef __attribute__((ext_vector_type(8))) short short8;
typedef __attribute__((ext_vector_type(4))) float floatx4;

__device__ __forceinline__ ushort f2bf_rne(float f) {
    unsigned u = __float_as_uint(f);
    unsigned r = u + 0x7FFFu + ((u >> 16) & 1u);
    return (ushort)(r >> 16);
}

// ---- fused prep: K -> bf16 straight; V -> bf16 transposed [bh][d][s] ----
__global__ __launch_bounds__(256)
void prep_kv(const float* __restrict__ K, const float* __restrict__ V,
             ushort* __restrict__ Kbf, ushort* __restrict__ Vt) {
    const int bh = blockIdx.y, s0 = blockIdx.x * 128, t = threadIdx.x;
    const size_t base = ((size_t)bh * SEQ + s0) * DH;
    {   // K: 32 consecutive floats per thread, short8 stores
        const float* src = K + base + t * 32;
        ushort* dst = Kbf + base + t * 32;
        #pragma unroll
        for (int h = 0; h < 4; ++h) {
            float4 a = *(const float4*)(src + h * 8);
            float4 b = *(const float4*)(src + h * 8 + 4);
            short8 o;
            o[0] = (short)f2bf_rne(a.x); o[1] = (short)f2bf_rne(a.y);
            o[2] = (short)f2bf_rne(a.z); o[3] = (short)f2bf_rne(a.w);
            o[4] = (short)f2bf_rne(b.x); o[5] = (short)f2bf_rne(b.y);
            o[6] = (short)f2bf_rne(b.z); o[7] = (short)f2bf_rne(b.w);
            *(short8*)(dst + h * 8) = o;
        }
    }
    {   // V: 4d x 8s register transpose, 16B stores along s
        const int d0 = (t & 15) * 4, sl = (t >> 4) * 8;
        const float* src = V + base + (size_t)sl * DH + d0;
        ushort* dst = Vt + (size_t)bh * DH * SEQ + s0 + sl;
        ushort b[8][4];
        #pragma unroll
        for (int r = 0; r < 8; ++r) {
            float4 f = *(const float4*)(src + r * DH);
            b[r][0] = f2bf_rne(f.x); b[r][1] = f2bf_rne(f.y);
            b[r][2] = f2bf_rne(f.z); b[r][3] = f2bf_rne(f.w);
        }
        #pragma unroll
        for (int i = 0; i < 4; ++i) {
            short8 w;
            #pragma unroll
            for (int r = 0; r < 8; ++r) w[r] = (short)b[r][i];
            *(short8*)(dst + (size_t)(d0 + i) * SEQ) = w;
        }
    }
}

// ---- main: barrier-free flash attention; K/V frags loaded global->VGPR ----
__global__ __launch_bounds__(256, 4)
void attn_fwd_v5(const float* __restrict__ Q, const ushort* __restrict__ Kbf,
                 const ushort* __restrict__ Vt, float* __restrict__ O)
{
    __shared__ __align__(16) char smem[17664];   // sP (10240 B) overlaid by epilogue

    // XCD-locality swizzle: XCD ~ blockIdx.x % 8; 2 bh per XCD
    const int g    = blockIdx.x;
    const int bh   = (g & 7) * 2 + ((g >> 3) & 1);
    const int qt0  = (g >> 4) * 64;

    const int tid   = threadIdx.x;
    const int wave  = tid >> 6;
    const int widx  = wave & 1;    // q-half
    const int wpair = wave >> 1;   // key-half
    const int lane  = tid & 63;
    const int n16   = lane & 15;
    const int quad  = lane >> 4;

    const float* Qb  = Q + ((size_t)bh * SEQ) * DH;
    const char*  KbB = (const char*)(Kbf + (size_t)bh * SEQ * DH);
    const char*  VtB = (const char*)(Vt  + (size_t)bh * DH * SEQ);
    float*       Ob  = O + ((size_t)bh * SEQ) * DH;

    ushort* sPw = (ushort*)smem + wave * (32 * PS);   // per-wave private

    // Q B-frags for 2 q-tiles; log2(e)/16 folded in (exp arg = raw score)
    const int qw0 = qt0 + widx * 32;
    short8 qfrag[2][2];
    #pragma unroll
    for (int qt = 0; qt < 2; ++qt) {
        const float* qrow = Qb + (size_t)(qw0 + qt * 16 + n16) * DH;
        #pragma unroll
        for (int t = 0; t < 2; ++t) {
            const float* p = qrow + t * 32 + quad * 8;
            short8 a;
            #pragma unroll
            for (int j = 0; j < 8; ++j) a[j] = (short)f2bf_rne(p[j] * QSCALE);
            qfrag[qt][t] = a;
        }
    }
    short8 ones;
    #pragma unroll
    for (int j = 0; j < 8; ++j) ones[j] = (short)0x3F80;   // bf16 1.0

    // per-lane byte offsets for direct fragment loads (coalesced 16B/lane)
    int kOff[2][2], vOff[4];
    #pragma unroll
    for (int kt = 0; kt < 2; ++kt)
        #pragma unroll
        for (int t = 0; t < 2; ++t)
            kOff[kt][t] = (kt * 16 + n16) * 128 + t * 64 + quad * 16;
    #pragma unroll
    for (int nt = 0; nt < 4; ++nt)
        vOff[nt] = (nt * 16 + n16) * (SEQ * 2) + quad * 16;

    floatx4 oacc[2][4];   // O^T partial: [qt][d-block], row=d, col=q
    floatx4 lacc[2];      // l partial via ones-MFMA
    #pragma unroll
    for (int qt = 0; qt < 2; ++qt) {
        lacc[qt] = (floatx4){0.f, 0.f, 0.f, 0.f};
        #pragma unroll
        for (int nt = 0; nt < 4; ++nt) oacc[qt][nt] = (floatx4){0.f, 0.f, 0.f, 0.f};
    }

    const int k0 = wpair * (SEQ / 2);
    const char* kp0 = KbB + (size_t)k0 * 128;
    const char* vp0 = VtB + (size_t)k0 * 2;
    const char* kp = kp0;
    const char* vp = vp0;

    // preload first tile's fragments
    short8 kf[2][2], vf[4];
    #pragma unroll
    for (int kt = 0; kt < 2; ++kt)
        #pragma unroll
        for (int t = 0; t < 2; ++t)
            kf[kt][t] = *(const short8*)(kp + kOff[kt][t]);
    #pragma unroll
    for (int nt = 0; nt < 4; ++nt)
        vf[nt] = *(const short8*)(vp + vOff[nt]);

    for (int it = 0; it < NIT; ++it) {
        const char* kpn = (it + 1 < NIT) ? kp + KT * 128 : kp0;  // clamp: harmless re-read
        const char* vpn = (it + 1 < NIT) ? vp + KT * 2   : vp0;

        // ---- S^T = K·Q^T: row=key (quad*4+r), col=q (n16) ----
        floatx4 sacc[2][2];
        #pragma unroll
        for (int kt = 0; kt < 2; ++kt) {
            #pragma unroll
            for (int qt = 0; qt < 2; ++qt) {
                floatx4 acc = (floatx4){0.f, 0.f, 0.f, 0.f};
                acc = __builtin_amdgcn_mfma_f32_16x16x32_bf16(kf[kt][0], qfrag[qt][0], acc, 0, 0, 0);
                acc = __builtin_amdgcn_mfma_f32_16x16x32_bf16(kf[kt][1], qfrag[qt][1], acc, 0, 0, 0);
                sacc[kt][qt] = acc;
            }
        }
        // prefetch next K into the now-dead kf regs (used ~350 cyc later)
        #pragma unroll
        for (int kt = 0; kt < 2; ++kt)
            #pragma unroll
            for (int t = 0; t < 2; ++t)
                kf[kt][t] = *(const short8*)(kpn + kOff[kt][t]);

        // ---- exp2 (scale pre-folded; global P-scale cancels in the final ratio) ----
        #pragma unroll
        for (int kt = 0; kt < 2; ++kt) {
            #pragma unroll
            for (int qt = 0; qt < 2; ++qt) {
                unsigned u0 = __float_as_uint(__builtin_amdgcn_exp2f(sacc[kt][qt][0]));
                unsigned u1 = __float_as_uint(__builtin_amdgcn_exp2f(sacc[kt][qt][1]));
                unsigned u2 = __float_as_uint(__builtin_amdgcn_exp2f(sacc[kt][qt][2]));
                unsigned u3 = __float_as_uint(__builtin_amdgcn_exp2f(sacc[kt][qt][3]));
                uint2 w;
                w.x = __builtin_amdgcn_perm(u1, u0, 0x07060302);  // [p0.hi, p1.hi]
                w.y = __builtin_amdgcn_perm(u3, u2, 0x07060302);  // [p2.hi, p3.hi]
                *(uint2*)&sPw[(qt * 16 + n16) * PS + kt * 16 + quad * 4] = w;
            }
        }

        // ---- P round-trip (wave-private, lgkmcnt only — no barrier) ----
        short8 pf[2];
        #pragma unroll
        for (int qt = 0; qt < 2; ++qt)
            pf[qt] = *(const short8*)&sPw[(qt * 16 + n16) * PS + quad * 8];

        // ---- O^T += V^T·P^T ----
        #pragma unroll
        for (int nt = 0; nt < 4; ++nt) {
            short8 v = vf[nt];
            #pragma unroll
            for (int qt = 0; qt < 2; ++qt)
                oacc[qt][nt] = __builtin_amdgcn_mfma_f32_16x16x32_bf16(v, pf[qt], oacc[qt][nt], 0, 0, 0);
        }
        // prefetch next V into now-dead vf regs
        #pragma unroll
        for (int nt = 0; nt < 4; ++nt)
            vf[nt] = *(const short8*)(vpn + vOff[nt]);

        // ---- l += ones·P^T (same truncated P̃ as numerator -> exact ratio) ----
        #pragma unroll
        for (int qt = 0; qt < 2; ++qt)
            lacc[qt] = __builtin_amdgcn_mfma_f32_16x16x32_bf16(ones, pf[qt], lacc[qt], 0, 0, 0);

        kp = kpn; vp = vpn;
    }

    // ---- epilogue: combine the two key-halves through LDS, store O ----
    __syncthreads();
    float* epiO = (float*)smem;               // [widx*32+q][68] fp32
    float* epiL = (float*)(smem + 17408);     // [64]
    if (wpair == 1) {
        #pragma unroll
        for (int qt = 0; qt < 2; ++qt) {
            const int row = widx * 32 + qt * 16 + n16;
            #pragma unroll
            for (int nt = 0; nt < 4; ++nt)
                *(float4*)&epiO[row * 68 + nt * 16 + quad * 4] = (float4){
                    oacc[qt][nt][0], oacc[qt][nt][1], oacc[qt][nt][2], oacc[qt][nt][3]};
            if (quad == 0) epiL[row] = lacc[qt][0];
        }
    }
    __syncthreads();
    if (wpair == 0) {
        #pragma unroll
        for (int qt = 0; qt < 2; ++qt) {
            const int row = widx * 32 + qt * 16 + n16;
            const float inv = 1.0f / (lacc[qt][0] + epiL[row]);
            const int q = qw0 + qt * 16 + n16;
            #pragma unroll
            for (int nt = 0; nt < 4; ++nt) {
                float4 part = *(const float4*)&epiO[row * 68 + nt * 16 + quad * 4];
                float4 o;
                o.x = (oacc[qt][nt][0] + part.x) * inv;
                o.y = (oacc[qt][nt][1] + part.y) * inv;
                o.z = (oacc[qt][nt][2] + part.z) * inv;
                o.w = (oacc[qt][nt][3] + part.w) * inv;
                *(float4*)&Ob[(size_t)q * DH + nt * 16 + quad * 4] = o;
            }
        }
    }
}

// ---------------- fallback (fp32-direct) if ws too small ----------------
__global__ __launch_bounds__(256, 4)
void attn_fwd_v1(const float* __restrict__ Q, const float* __restrict__ K,
                 const float* __restrict__ V, float* __restrict__ O)
{
    __shared__ __align__(16) ushort sKf[64 * 72];
    __shared__ __align__(16) ushort sVf[64 * 72];
    __shared__ __align__(16) ushort sPf[4 * 16 * 72];
    const int bh = blockIdx.y, qt0 = blockIdx.x * 64, tid = threadIdx.x;
    const int wave = tid >> 6, lane = tid & 63, n16 = lane & 15, quad = lane >> 4;
    const size_t base = (size_t)bh * SEQ * DH;
    const float *Qb = Q + base, *Kb = K + base, *Vb = V + base;
    float* Ob = O + base;
    short8 qfrag[2];
    {
        const float* qrow = Qb + (size_t)(qt0 + wave * 16 + n16) * DH;
        #pragma unroll
        for (int t = 0; t < 2; ++t) {
            const float* p = qrow + t * 32 + quad * 8;
            short8 a;
            #pragma unroll
            for (int j = 0; j < 8; ++j) a[j] = (short)f2bf_rne(p[j] * 0.0625f);
            qfrag[t] = a;
        }
    }
    floatx4 oacc[4];
    #pragma unroll
    for (int nt = 0; nt < 4; ++nt) oacc[nt] = (floatx4){0.f,0.f,0.f,0.f};
    float m_i[4] = {-INFINITY,-INFINITY,-INFINITY,-INFINITY};
    float l_i[4] = {0.f,0.f,0.f,0.f};
    const int skr = tid >> 2, sc0 = (tid & 3) * 16;
    for (int kt0 = 0; kt0 < SEQ; kt0 += 64) {
        __syncthreads();
        const float* ksrc = Kb + (size_t)(kt0 + skr) * DH + sc0;
        const float* vsrc = Vb + (size_t)(kt0 + skr) * DH + sc0;
        ushort* kdst = &sKf[skr * 72 + sc0];
        #pragma unroll
        for (int i = 0; i < 16; i += 4) {
            float4 kf = *(const float4*)(ksrc + i);
            kdst[i+0]=f2bf_rne(kf.x); kdst[i+1]=f2bf_rne(kf.y);
            kdst[i+2]=f2bf_rne(kf.z); kdst[i+3]=f2bf_rne(kf.w);
            float4 vf = *(const float4*)(vsrc + i);
            sVf[(sc0+i+0)*72+skr]=f2bf_rne(vf.x); sVf[(sc0+i+1)*72+skr]=f2bf_rne(vf.y);
            sVf[(sc0+i+2)*72+skr]=f2bf_rne(vf.z); sVf[(sc0+i+3)*72+skr]=f2bf_rne(vf.w);
        }
        __syncthreads();
        floatx4 sacc[4];
        #pragma unroll
        for (int nt = 0; nt < 4; ++nt) {
            sacc[nt] = (floatx4){0.f,0.f,0.f,0.f};
            #pragma unroll
            for (int t = 0; t < 2; ++t) {
                short8 b = *(const short8*)&sKf[(nt*16+n16)*72 + t*32 + quad*8];
                sacc[nt] = __builtin_amdgcn_mfma_f32_16x16x32_bf16(qfrag[t], b, sacc[nt], 0,0,0);
            }
        }
        ushort* pw = &sPf[wave * 16 * 72];
        #pragma unroll
        for (int r = 0; r < 4; ++r) {
            float mx = fmaxf(fmaxf(sacc[0][r],sacc[1][r]),fmaxf(sacc[2][r],sacc[3][r]));
            #pragma unroll
            for (int off = 1; off < 16; off <<= 1) mx = fmaxf(mx, __shfl_xor(mx, off, 64));
            float mnew = fmaxf(m_i[r], mx);
            float alpha = __expf(m_i[r] - mnew);
            m_i[r] = mnew;
            float sum = 0.f;
            #pragma unroll
            for (int nt = 0; nt < 4; ++nt) {
                float p = __expf(sacc[nt][r] - mnew);
                sacc[nt][r] = p; sum += p;
            }
            #pragma unroll
            for (int off = 1; off < 16; off <<= 1) sum += __shfl_xor(sum, off, 64);
            l_i[r] = l_i[r] * alpha + sum;
            #pragma unroll
            for (int nt = 0; nt < 4; ++nt) oacc[nt][r] *= alpha;
            #pragma unroll
            for (int nt = 0; nt < 4; ++nt)
                pw[(quad*4+r)*72 + nt*16 + n16] = f2bf_rne(sacc[nt][r]);
        }
        #pragma unroll
        for (int t = 0; t < 2; ++t) {
            short8 pfr = *(const short8*)&pw[n16*72 + t*32 + quad*8];
            #pragma unroll
            for (int nt = 0; nt < 4; ++nt) {
                short8 vfr = *(const short8*)&sVf[(nt*16+n16)*72 + t*32 + quad*8];
                oacc[nt] = __builtin_amdgcn_mfma_f32_16x16x32_bf16(pfr, vfr, oacc[nt], 0,0,0);
            }
        }
    }
    #pragma unroll
    for (int r = 0; r < 4; ++r) {
        float inv = 1.0f / l_i[r];
        float* orow = Ob + (size_t)(qt0 + wave*16 + quad*4 + r) * DH;
        #pragma unroll
        for (int nt = 0; nt < 4; ++nt) orow[nt*16+n16] = oacc[nt][r] * inv;
    }
}

extern "C" void kernel_launch(void* const* d_in, const int* in_sizes, int n_in,
                              void* d_out, int out_size, void* d_ws, size_t ws_size,
                              hipStream_t stream) {
    const float* q = (const float*)d_in[0];
    const float* k = (const float*)d_in[1];
    const float* v = (const float*)d_in[2];
    float* o = (float*)d_out;
    const size_t elems = (size_t)16 * SEQ * DH;
    const size_t need  = elems * 2 * 2;     // Kbf + Vt, bf16
    if (ws_size >= need) {
        ushort* kbf = (ushort*)d_ws;
        ushort* vt  = kbf + elems;
        prep_kv<<<dim3(SEQ / 128, 16), dim3(256), 0, stream>>>(k, v, kbf, vt);
        attn_fwd_v5<<<dim3(1024), dim3(256), 0, stream>>>(q, kbf, vt, o);
    } else {
        attn_fwd_v1<<<dim3(SEQ / 64, 16), dim3(256), 0, stream>>>(q, k, v, o);
    }
}

// Round 6
// 184.873 us; speedup vs baseline: 1.7344x; 1.7344x over previous
//
#include <hip/hip_runtime.h>
#include <hip/hip_bf16.h>
#include <stdint.h>

#define SEQ 4096
#define DH  64
#define KT  32                 // keys per iteration per key-half
#define PS  40                 // sP row stride in ushorts (80 B)
#define NIT ((SEQ / 2) / KT)   // 64 iterations
#define QSCALE 0.090168440f    // log2(e)/16 folded into Q

typedef __attribute__((ext_vector_type(8))) short short8;
typedef __attribute__((ext_vector_type(4))) float floatx4;

__device__ __forceinline__ ushort f2bf_rne(float f) {
    unsigned u = __float_as_uint(f);
    unsigned r = u + 0x7FFFu + ((u >> 16) & 1u);
    return (ushort)(r >> 16);
}

__device__ __forceinline__ void async_copy16(void* lds, const void* gsrc) {
    __builtin_amdgcn_global_load_lds(
        (const __attribute__((address_space(1))) uint32_t*)gsrc,
        (__attribute__((address_space(3))) uint32_t*)lds, 16, 0, 0);
}

// ---- fused prep: K -> bf16 straight; V -> bf16 transposed [bh][d][s] ----
__global__ __launch_bounds__(256)
void prep_kv(const float* __restrict__ K, const float* __restrict__ V,
             ushort* __restrict__ Kbf, ushort* __restrict__ Vt) {
    const int bh = blockIdx.y, s0 = blockIdx.x * 128, t = threadIdx.x;
    const size_t base = ((size_t)bh * SEQ + s0) * DH;
    {   // K: 32 consecutive floats per thread, short8 stores
        const float* src = K + base + t * 32;
        ushort* dst = Kbf + base + t * 32;
        #pragma unroll
        for (int h = 0; h < 4; ++h) {
            float4 a = *(const float4*)(src + h * 8);
            float4 b = *(const float4*)(src + h * 8 + 4);
            short8 o;
            o[0] = (short)f2bf_rne(a.x); o[1] = (short)f2bf_rne(a.y);
            o[2] = (short)f2bf_rne(a.z); o[3] = (short)f2bf_rne(a.w);
            o[4] = (short)f2bf_rne(b.x); o[5] = (short)f2bf_rne(b.y);
            o[6] = (short)f2bf_rne(b.z); o[7] = (short)f2bf_rne(b.w);
            *(short8*)(dst + h * 8) = o;
        }
    }
    {   // V: 4d x 8s register transpose, 16B stores along s
        const int d0 = (t & 15) * 4, sl = (t >> 4) * 8;
        const float* src = V + base + (size_t)sl * DH + d0;
        ushort* dst = Vt + (size_t)bh * DH * SEQ + s0 + sl;
        ushort b[8][4];
        #pragma unroll
        for (int r = 0; r < 8; ++r) {
            float4 f = *(const float4*)(src + r * DH);
            b[r][0] = f2bf_rne(f.x); b[r][1] = f2bf_rne(f.y);
            b[r][2] = f2bf_rne(f.z); b[r][3] = f2bf_rne(f.w);
        }
        #pragma unroll
        for (int i = 0; i < 4; ++i) {
            short8 w;
            #pragma unroll
            for (int r = 0; r < 8; ++r) w[r] = (short)b[r][i];
            *(short8*)(dst + (size_t)(d0 + i) * SEQ) = w;
        }
    }
}

// ---- main: split-K flash attention, LDS staging with overlapped DMA ----
__global__ __launch_bounds__(256, 4)
void attn_fwd_v6(const float* __restrict__ Q, const ushort* __restrict__ Kbf,
                 const ushort* __restrict__ Vt, float* __restrict__ O)
{
    // sK 8KB | sVt 8KB | sP 10KB ; epilogue overlays from 0
    __shared__ __align__(16) char smem[26624];

    // XCD-locality swizzle: consecutive blocks spread over XCDs, 2 bh per XCD
    const int g    = blockIdx.x;
    const int bh   = (g & 7) * 2 + ((g >> 3) & 1);
    const int qt0  = (g >> 4) * 64;

    const int tid   = threadIdx.x;
    const int wave  = tid >> 6;
    const int widx  = wave & 1;    // q-half
    const int wpair = wave >> 1;   // key-half
    const int lane  = tid & 63;
    const int n16   = lane & 15;
    const int quad  = lane >> 4;

    const float* Qb  = Q + ((size_t)bh * SEQ) * DH;
    const char*  KbB = (const char*)(Kbf + (size_t)bh * SEQ * DH);
    const char*  VtB = (const char*)(Vt  + (size_t)bh * DH * SEQ);
    float*       Ob  = O + ((size_t)bh * SEQ) * DH;

    ushort* sK  = (ushort*)(smem)         + wpair * 2048;   // [key 0..31][d 0..63]
    ushort* sVt = (ushort*)(smem + 8192)  + wpair * 2048;   // [d 0..63][key 0..31]
    ushort* sPw = (ushort*)(smem + 16384) + wave  * 1280;   // [q 0..31][key 0..31]

    // Q B-frags: log2(e)/16 folded (exp2 arg = raw score accumulator)
    const int qw0 = qt0 + widx * 32;
    short8 qfrag[2][2];
    #pragma unroll
    for (int qt = 0; qt < 2; ++qt) {
        const float* qrow = Qb + (size_t)(qw0 + qt * 16 + n16) * DH;
        #pragma unroll
        for (int t = 0; t < 2; ++t) {
            const float* p = qrow + t * 32 + quad * 8;
            short8 a;
            #pragma unroll
            for (int j = 0; j < 8; ++j) a[j] = (short)f2bf_rne(p[j] * QSCALE);
            qfrag[qt][t] = a;
        }
    }
    short8 ones;
    #pragma unroll
    for (int j = 0; j < 8; ++j) ones[j] = (short)0x3F80;   // bf16 1.0

    // staging offsets: per wave 2 K-chunks + 2 V-chunks of 1 KB (XOR-swizzled)
    int kGoff[2], vGoff[2];
    char *kDst[2], *vDst[2];
    #pragma unroll
    for (int c = 0; c < 2; ++c) {
        int L = (c * 2 + widx) * 1024 + lane * 16;
        int krow = L >> 7, kp = (L >> 4) & 7;
        kGoff[c] = krow * 128 + ((kp ^ (krow & 7)) * 16);
        kDst[c]  = (char*)sK + L;
        int vrow = L >> 6, vp = (L >> 4) & 3;
        vGoff[c] = vrow * (SEQ * 2) + ((vp ^ (vrow & 3)) * 16);
        vDst[c]  = (char*)sVt + L;
    }
    // swizzled within-row fragment offsets (ushorts)
    const int sw0  = ((0 + quad) ^ (n16 & 7)) * 8;   // K row chunk t=0
    const int sw1  = ((4 + quad) ^ (n16 & 7)) * 8;   // K row chunk t=1
    const int sw_v = ((quad) ^ (n16 & 3)) * 8;       // V row chunk

    floatx4 oacc[2][4];   // O^T partial: [qt][d-block], row=d, col=q
    floatx4 lacc[2];      // l partial via ones-MFMA
    #pragma unroll
    for (int qt = 0; qt < 2; ++qt) {
        lacc[qt] = (floatx4){0.f, 0.f, 0.f, 0.f};
        #pragma unroll
        for (int nt = 0; nt < 4; ++nt) oacc[qt][nt] = (floatx4){0.f, 0.f, 0.f, 0.f};
    }

    const int k0 = wpair * (SEQ / 2);

    // preload tile 0
    {
        const size_t kb = (size_t)k0;
        async_copy16(kDst[0], KbB + kb * 128 + kGoff[0]);
        async_copy16(kDst[1], KbB + kb * 128 + kGoff[1]);
        async_copy16(vDst[0], VtB + kb * 2   + vGoff[0]);
        async_copy16(vDst[1], VtB + kb * 2   + vGoff[1]);
    }
    __syncthreads();   // drain tile 0

    for (int it = 0; it < NIT; ++it) {
        // ---- read ALL fragments of the resident tile into registers ----
        short8 kf[2][2], vf[4];
        #pragma unroll
        for (int kt = 0; kt < 2; ++kt) {
            kf[kt][0] = *(const short8*)&sK[(kt * 16 + n16) * 64 + sw0];
            kf[kt][1] = *(const short8*)&sK[(kt * 16 + n16) * 64 + sw1];
        }
        #pragma unroll
        for (int nt = 0; nt < 4; ++nt)
            vf[nt] = *(const short8*)&sVt[(nt * 16 + n16) * 32 + sw_v];

        __syncthreads();   // all waves done reading LDS (lgkm-only, cheap)

        // ---- issue DMA for next tile; it ages across the whole compute phase ----
        if (it + 1 < NIT) {
            const size_t kb = (size_t)(k0 + (it + 1) * KT);
            async_copy16(kDst[0], KbB + kb * 128 + kGoff[0]);
            async_copy16(kDst[1], KbB + kb * 128 + kGoff[1]);
            async_copy16(vDst[0], VtB + kb * 2   + vGoff[0]);
            async_copy16(vDst[1], VtB + kb * 2   + vGoff[1]);
        }

        // ---- S^T = K·Q^T: row=key (quad*4+r), col=q (n16) ----
        floatx4 sacc[2][2];
        #pragma unroll
        for (int kt = 0; kt < 2; ++kt) {
            #pragma unroll
            for (int qt = 0; qt < 2; ++qt) {
                floatx4 acc = (floatx4){0.f, 0.f, 0.f, 0.f};
                acc = __builtin_amdgcn_mfma_f32_16x16x32_bf16(kf[kt][0], qfrag[qt][0], acc, 0, 0, 0);
                acc = __builtin_amdgcn_mfma_f32_16x16x32_bf16(kf[kt][1], qfrag[qt][1], acc, 0, 0, 0);
                sacc[kt][qt] = acc;
            }
        }

        // ---- exp2 (scale folded; global P-scale cancels in final ratio) ----
        #pragma unroll
        for (int kt = 0; kt < 2; ++kt) {
            #pragma unroll
            for (int qt = 0; qt < 2; ++qt) {
                unsigned u0 = __float_as_uint(__builtin_amdgcn_exp2f(sacc[kt][qt][0]));
                unsigned u1 = __float_as_uint(__builtin_amdgcn_exp2f(sacc[kt][qt][1]));
                unsigned u2 = __float_as_uint(__builtin_amdgcn_exp2f(sacc[kt][qt][2]));
                unsigned u3 = __float_as_uint(__builtin_amdgcn_exp2f(sacc[kt][qt][3]));
                uint2 w;
                w.x = __builtin_amdgcn_perm(u1, u0, 0x07060302);  // [p0.hi, p1.hi]
                w.y = __builtin_amdgcn_perm(u3, u2, 0x07060302);  // [p2.hi, p3.hi]
                *(uint2*)&sPw[(qt * 16 + n16) * PS + kt * 16 + quad * 4] = w;
            }
        }

        // ---- P round-trip (wave-private, lgkm-only) ----
        short8 pf[2];
        #pragma unroll
        for (int qt = 0; qt < 2; ++qt)
            pf[qt] = *(const short8*)&sPw[(qt * 16 + n16) * PS + quad * 8];

        // ---- O^T += V^T·P^T ; l += ones·P^T ----
        #pragma unroll
        for (int nt = 0; nt < 4; ++nt) {
            short8 v = vf[nt];
            #pragma unroll
            for (int qt = 0; qt < 2; ++qt)
                oacc[qt][nt] = __builtin_amdgcn_mfma_f32_16x16x32_bf16(v, pf[qt], oacc[qt][nt], 0, 0, 0);
        }
        #pragma unroll
        for (int qt = 0; qt < 2; ++qt)
            lacc[qt] = __builtin_amdgcn_mfma_f32_16x16x32_bf16(ones, pf[qt], lacc[qt], 0, 0, 0);

        __syncthreads();   // drain aged DMA; gate next iteration's reads
    }

    // ---- epilogue: combine key-halves through LDS (overlay), store O ----
    float* epiO = (float*)smem;               // [widx*32+q][68] fp32
    float* epiL = (float*)(smem + 17408);     // [64]
    if (wpair == 1) {
        #pragma unroll
        for (int qt = 0; qt < 2; ++qt) {
            const int row = widx * 32 + qt * 16 + n16;
            #pragma unroll
            for (int nt = 0; nt < 4; ++nt)
                *(float4*)&epiO[row * 68 + nt * 16 + quad * 4] = (float4){
                    oacc[qt][nt][0], oacc[qt][nt][1], oacc[qt][nt][2], oacc[qt][nt][3]};
            if (quad == 0) epiL[row] = lacc[qt][0];
        }
    }
    __syncthreads();
    if (wpair == 0) {
        #pragma unroll
        for (int qt = 0; qt < 2; ++qt) {
            const int row = widx * 32 + qt * 16 + n16;
            const float inv = 1.0f / (lacc[qt][0] + epiL[row]);
            const int q = qw0 + qt * 16 + n16;
            #pragma unroll
            for (int nt = 0; nt < 4; ++nt) {
                float4 part = *(const float4*)&epiO[row * 68 + nt * 16 + quad * 4];
                float4 o;
                o.x = (oacc[qt][nt][0] + part.x) * inv;
                o.y = (oacc[qt][nt][1] + part.y) * inv;
                o.z = (oacc[qt][nt][2] + part.z) * inv;
                o.w = (oacc[qt][nt][3] + part.w) * inv;
                *(float4*)&Ob[(size_t)q * DH + nt * 16 + quad * 4] = o;
            }
        }
    }
}

// ---------------- fallback (fp32-direct) if ws too small ----------------
__global__ __launch_bounds__(256, 4)
void attn_fwd_v1(const float* __restrict__ Q, const float* __restrict__ K,
                 const float* __restrict__ V, float* __restrict__ O)
{
    __shared__ __align__(16) ushort sKf[64 * 72];
    __shared__ __align__(16) ushort sVf[64 * 72];
    __shared__ __align__(16) ushort sPf[4 * 16 * 72];
    const int bh = blockIdx.y, qt0 = blockIdx.x * 64, tid = threadIdx.x;
    const int wave = tid >> 6, lane = tid & 63, n16 = lane & 15, quad = lane >> 4;
    const size_t base = (size_t)bh * SEQ * DH;
    const float *Qb = Q + base, *Kb = K + base, *Vb = V + base;
    float* Ob = O + base;
    short8 qfrag[2];
    {
        const float* qrow = Qb + (size_t)(qt0 + wave * 16 + n16) * DH;
        #pragma unroll
        for (int t = 0; t < 2; ++t) {
            const float* p = qrow + t * 32 + quad * 8;
            short8 a;
            #pragma unroll
            for (int j = 0; j < 8; ++j) a[j] = (short)f2bf_rne(p[j] * 0.0625f);
            qfrag[t] = a;
        }
    }
    floatx4 oacc[4];
    #pragma unroll
    for (int nt = 0; nt < 4; ++nt) oacc[nt] = (floatx4){0.f,0.f,0.f,0.f};
    float m_i[4] = {-INFINITY,-INFINITY,-INFINITY,-INFINITY};
    float l_i[4] = {0.f,0.f,0.f,0.f};
    const int skr = tid >> 2, sc0 = (tid & 3) * 16;
    for (int kt0 = 0; kt0 < SEQ; kt0 += 64) {
        __syncthreads();
        const float* ksrc = Kb + (size_t)(kt0 + skr) * DH + sc0;
        const float* vsrc = Vb + (size_t)(kt0 + skr) * DH + sc0;
        ushort* kdst = &sKf[skr * 72 + sc0];
        #pragma unroll
        for (int i = 0; i < 16; i += 4) {
            float4 kf = *(const float4*)(ksrc + i);
            kdst[i+0]=f2bf_rne(kf.x); kdst[i+1]=f2bf_rne(kf.y);
            kdst[i+2]=f2bf_rne(kf.z); kdst[i+3]=f2bf_rne(kf.w);
            float4 vf = *(const float4*)(vsrc + i);
            sVf[(sc0+i+0)*72+skr]=f2bf_rne(vf.x); sVf[(sc0+i+1)*72+skr]=f2bf_rne(vf.y);
            sVf[(sc0+i+2)*72+skr]=f2bf_rne(vf.z); sVf[(sc0+i+3)*72+skr]=f2bf_rne(vf.w);
        }
        __syncthreads();
        floatx4 sacc[4];
        #pragma unroll
        for (int nt = 0; nt < 4; ++nt) {
            sacc[nt] = (floatx4){0.f,0.f,0.f,0.f};
            #pragma unroll
            for (int t = 0; t < 2; ++t) {
                short8 b = *(const short8*)&sKf[(nt*16+n16)*72 + t*32 + quad*8];
                sacc[nt] = __builtin_amdgcn_mfma_f32_16x16x32_bf16(qfrag[t], b, sacc[nt], 0,0,0);
            }
        }
        ushort* pw = &sPf[wave * 16 * 72];
        #pragma unroll
        for (int r = 0; r < 4; ++r) {
            float mx = fmaxf(fmaxf(sacc[0][r],sacc[1][r]),fmaxf(sacc[2][r],sacc[3][r]));
            #pragma unroll
            for (int off = 1; off < 16; off <<= 1) mx = fmaxf(mx, __shfl_xor(mx, off, 64));
            float mnew = fmaxf(m_i[r], mx);
            float alpha = __expf(m_i[r] - mnew);
            m_i[r] = mnew;
            float sum = 0.f;
            #pragma unroll
            for (int nt = 0; nt < 4; ++nt) {
                float p = __expf(sacc[nt][r] - mnew);
                sacc[nt][r] = p; sum += p;
            }
            #pragma unroll
            for (int off = 1; off < 16; off <<= 1) sum += __shfl_xor(sum, off, 64);
            l_i[r] = l_i[r] * alpha + sum;
            #pragma unroll
            for (int nt = 0; nt < 4; ++nt) oacc[nt][r] *= alpha;
            #pragma unroll
            for (int nt = 0; nt < 4; ++nt)
                pw[(quad*4+r)*72 + nt*16 + n16] = f2bf_rne(sacc[nt][r]);
        }
        #pragma unroll
        for (int t = 0; t < 2; ++t) {
            short8 pfr = *(const short8*)&pw[n16*72 + t*32 + quad*8];
            #pragma unroll
            for (int nt = 0; nt < 4; ++nt) {
                short8 vfr = *(const short8*)&sVf[(nt*16+n16)*72 + t*32 + quad*8];
                oacc[nt] = __builtin_amdgcn_mfma_f32_16x16x32_bf16(pfr, vfr, oacc[nt], 0,0,0);
            }
        }
    }
    #pragma unroll
    for (int r = 0; r < 4; ++r) {
        float inv = 1.0f / l_i[r];
        float* orow = Ob + (size_t)(qt0 + wave*16 + quad*4 + r) * DH;
        #pragma unroll
        for (int nt = 0; nt < 4; ++nt) orow[nt*16+n16] = oacc[nt][r] * inv;
    }
}

extern "C" void kernel_launch(void* const* d_in, const int* in_sizes, int n_in,
                              void* d_out, int out_size, void* d_ws, size_t ws_size,
                              hipStream_t stream) {
    const float* q = (const float*)d_in[0];
    const float* k = (const float*)d_in[1];
    const float* v = (const float*)d_in[2];
    float* o = (float*)d_out;
    const size_t elems = (size_t)16 * SEQ * DH;
    const size_t need  = elems * 2 * 2;     // Kbf + Vt, bf16
    if (ws_size >= need) {
        ushort* kbf = (ushort*)d_ws;
        ushort* vt  = kbf + elems;
        prep_kv<<<dim3(SEQ / 128, 16), dim3(256), 0, stream>>>(k, v, kbf, vt);
        attn_fwd_v6<<<dim3(1024), dim3(256), 0, stream>>>(q, kbf, vt, o);
    } else {
        attn_fwd_v1<<<dim3(SEQ / 64, 16), dim3(256), 0, stream>>>(q, k, v, o);
    }
}

// Round 7
// 168.572 us; speedup vs baseline: 1.9022x; 1.0967x over previous
//
#include <hip/hip_runtime.h>
#include <hip/hip_bf16.h>
#include <stdint.h>

#define SEQ 4096
#define DH  64
#define KT  32                 // keys per iteration per key-half
#define PS  40                 // sP row stride in ushorts (80 B)
#define NIT ((SEQ / 2) / KT)   // 64 iterations
#define QSCALE 0.090168440f    // log2(e)/16 folded into Q

typedef __attribute__((ext_vector_type(8))) short short8;
typedef __attribute__((ext_vector_type(4))) float floatx4;

__device__ __forceinline__ ushort f2bf_rne(float f) {
    unsigned u = __float_as_uint(f);
    unsigned r = u + 0x7FFFu + ((u >> 16) & 1u);
    return (ushort)(r >> 16);
}

// ---- prep: K,V -> bf16 in MFMA-fragment-permuted order ----
// Kf: per 16-key group g (2048 B): chunk(t,lam) 16B = K[key=g*16+(lam&15)][d=t*32+(lam>>4)*8 ..+8]
// Vf: per 32-key tile T (4096 B): chunk(nt,lam) 16B = V^T[d=nt*16+(lam&15)][key=T*32+(lam>>4)*8 ..+8]
__global__ __launch_bounds__(256)
void prep_kv(const float* __restrict__ K, const float* __restrict__ V,
             ushort* __restrict__ Kf, ushort* __restrict__ Vf) {
    const int bh = blockIdx.y, kb0 = blockIdx.x * 128, t = threadIdx.x;
    const size_t inB = ((size_t)bh * SEQ + kb0) * DH;
    {   // K part: 4 passes x 256 threads = 1024 chunks (8 groups)
        const float* srcB = K + inB;
        ushort* dstB = Kf + (size_t)bh * SEQ * DH + (size_t)(kb0 >> 4) * 1024;
        #pragma unroll
        for (int p = 0; p < 4; ++p) {
            int c   = p * 256 + t;
            int g   = c >> 7, rem = c & 127;
            int tt  = rem >> 6, lam = rem & 63;
            int key = g * 16 + (lam & 15);
            int d0  = tt * 32 + (lam >> 4) * 8;
            const float* s = srcB + (size_t)key * DH + d0;
            float4 a = *(const float4*)s;
            float4 b = *(const float4*)(s + 4);
            short8 o;
            o[0] = (short)f2bf_rne(a.x); o[1] = (short)f2bf_rne(a.y);
            o[2] = (short)f2bf_rne(a.z); o[3] = (short)f2bf_rne(a.w);
            o[4] = (short)f2bf_rne(b.x); o[5] = (short)f2bf_rne(b.y);
            o[6] = (short)f2bf_rne(b.z); o[7] = (short)f2bf_rne(b.w);
            *(short8*)(dstB + g * 1024 + tt * 512 + lam * 8) = o;
        }
    }
    {   // V part: 4d x 8key register transpose into permuted chunks
        const int d0 = (t & 15) * 4, sl = (t >> 4) * 8;
        const float* src = V + inB + (size_t)sl * DH + d0;
        ushort* dstB = Vf + (size_t)bh * SEQ * DH + (size_t)(kb0 >> 5) * 2048;
        ushort b[8][4];
        #pragma unroll
        for (int r = 0; r < 8; ++r) {
            float4 f = *(const float4*)(src + r * DH);
            b[r][0] = f2bf_rne(f.x); b[r][1] = f2bf_rne(f.y);
            b[r][2] = f2bf_rne(f.z); b[r][3] = f2bf_rne(f.w);
        }
        const int Tl = sl >> 5, kq = (sl & 31) >> 3;
        #pragma unroll
        for (int i = 0; i < 4; ++i) {
            int d = d0 + i;
            short8 w;
            #pragma unroll
            for (int r = 0; r < 8; ++r) w[r] = (short)b[r][i];
            *(short8*)(dstB + Tl * 2048 + (d >> 4) * 512 + kq * 128 + (d & 15) * 8) = w;
        }
    }
}

// ---- main: barrier-free K-loop; K/V frags direct global->VGPR (coalesced) ----
__global__ __launch_bounds__(256, 4)
void attn_fwd_v7(const float* __restrict__ Q, const ushort* __restrict__ Kf,
                 const ushort* __restrict__ Vf, float* __restrict__ O)
{
    __shared__ __align__(16) char smem[17664];   // sP 10 KB; epilogue overlays

    // XCD-locality swizzle: 2 bh per XCD
    const int g    = blockIdx.x;
    const int bh   = (g & 7) * 2 + ((g >> 3) & 1);
    const int qt0  = (g >> 4) * 64;

    const int tid   = threadIdx.x;
    const int wave  = tid >> 6;
    const int widx  = wave & 1;    // q-half
    const int wpair = wave >> 1;   // key-half
    const int lane  = tid & 63;
    const int n16   = lane & 15;
    const int quad  = lane >> 4;

    const float* Qb  = Q + ((size_t)bh * SEQ) * DH;
    const char*  KfB = (const char*)(Kf + (size_t)bh * SEQ * DH);
    const char*  VfB = (const char*)(Vf + (size_t)bh * SEQ * DH);
    float*       Ob  = O + ((size_t)bh * SEQ) * DH;

    ushort* sPw = (ushort*)smem + wave * (32 * PS);   // wave-private

    // Q B-frags; log2(e)/16 folded (exp2 arg = raw score)
    const int qw0 = qt0 + widx * 32;
    short8 qfrag[2][2];
    #pragma unroll
    for (int qt = 0; qt < 2; ++qt) {
        const float* qrow = Qb + (size_t)(qw0 + qt * 16 + n16) * DH;
        #pragma unroll
        for (int t = 0; t < 2; ++t) {
            const float* p = qrow + t * 32 + quad * 8;
            short8 a;
            #pragma unroll
            for (int j = 0; j < 8; ++j) a[j] = (short)f2bf_rne(p[j] * QSCALE);
            qfrag[qt][t] = a;
        }
    }
    short8 ones;
    #pragma unroll
    for (int j = 0; j < 8; ++j) ones[j] = (short)0x3F80;   // bf16 1.0

    floatx4 oacc[2][4];
    floatx4 lacc[2];
    #pragma unroll
    for (int qt = 0; qt < 2; ++qt) {
        lacc[qt] = (floatx4){0.f, 0.f, 0.f, 0.f};
        #pragma unroll
        for (int nt = 0; nt < 4; ++nt) oacc[qt][nt] = (floatx4){0.f, 0.f, 0.f, 0.f};
    }

    // per-lane base pointers (lane*16 folded in); both advance 4096 B/iter
    const char* kp0 = KfB + (size_t)wpair * 262144 + lane * 16;
    const char* vp0 = VfB + (size_t)wpair * 262144 + lane * 16;
    const char* kp = kp0;
    const char* vp = vp0;

    // preload tile 0 fragments (4 contiguous 1 KB chunks each)
    short8 kf[4], vf[4];
    #pragma unroll
    for (int c = 0; c < 4; ++c) kf[c] = *(const short8*)(kp + c * 1024);
    #pragma unroll
    for (int c = 0; c < 4; ++c) vf[c] = *(const short8*)(vp + c * 1024);

    for (int it = 0; it < NIT; ++it) {
        const char* kpn = (it + 1 < NIT) ? kp + 4096 : kp0;   // clamp: harmless re-read
        const char* vpn = (it + 1 < NIT) ? vp + 4096 : vp0;

        // ---- S^T = K·Q^T: kf[kt*2+t] = A-frag, row=key (quad*4+r), col=q (n16) ----
        floatx4 sacc[2][2];
        #pragma unroll
        for (int kt = 0; kt < 2; ++kt) {
            #pragma unroll
            for (int qt = 0; qt < 2; ++qt) {
                floatx4 acc = (floatx4){0.f, 0.f, 0.f, 0.f};
                acc = __builtin_amdgcn_mfma_f32_16x16x32_bf16(kf[kt * 2 + 0], qfrag[qt][0], acc, 0, 0, 0);
                acc = __builtin_amdgcn_mfma_f32_16x16x32_bf16(kf[kt * 2 + 1], qfrag[qt][1], acc, 0, 0, 0);
                sacc[kt][qt] = acc;
            }
        }
        // prefetch next K tile in place (consumed at next iter's QK)
        #pragma unroll
        for (int c = 0; c < 4; ++c) kf[c] = *(const short8*)(kpn + c * 1024);

        // ---- exp2 (scale folded; global P-scale cancels in final ratio) ----
        #pragma unroll
        for (int kt = 0; kt < 2; ++kt) {
            #pragma unroll
            for (int qt = 0; qt < 2; ++qt) {
                unsigned u0 = __float_as_uint(__builtin_amdgcn_exp2f(sacc[kt][qt][0]));
                unsigned u1 = __float_as_uint(__builtin_amdgcn_exp2f(sacc[kt][qt][1]));
                unsigned u2 = __float_as_uint(__builtin_amdgcn_exp2f(sacc[kt][qt][2]));
                unsigned u3 = __float_as_uint(__builtin_amdgcn_exp2f(sacc[kt][qt][3]));
                uint2 w;
                w.x = __builtin_amdgcn_perm(u1, u0, 0x07060302);  // [p0.hi, p1.hi]
                w.y = __builtin_amdgcn_perm(u3, u2, 0x07060302);  // [p2.hi, p3.hi]
                *(uint2*)&sPw[(qt * 16 + n16) * PS + kt * 16 + quad * 4] = w;
            }
        }

        // ---- P round-trip (wave-private LDS, lgkm-only; no barrier) ----
        short8 pf[2];
        #pragma unroll
        for (int qt = 0; qt < 2; ++qt)
            pf[qt] = *(const short8*)&sPw[(qt * 16 + n16) * PS + quad * 8];

        // ---- O^T += V^T·P^T ; l += ones·P^T ----
        #pragma unroll
        for (int nt = 0; nt < 4; ++nt) {
            short8 v = vf[nt];
            #pragma unroll
            for (int qt = 0; qt < 2; ++qt)
                oacc[qt][nt] = __builtin_amdgcn_mfma_f32_16x16x32_bf16(v, pf[qt], oacc[qt][nt], 0, 0, 0);
        }
        #pragma unroll
        for (int qt = 0; qt < 2; ++qt)
            lacc[qt] = __builtin_amdgcn_mfma_f32_16x16x32_bf16(ones, pf[qt], lacc[qt], 0, 0, 0);

        // prefetch next V tile in place (consumed at next iter's PV)
        #pragma unroll
        for (int c = 0; c < 4; ++c) vf[c] = *(const short8*)(vpn + c * 1024);

        kp = kpn; vp = vpn;
    }

    // ---- epilogue: combine key-halves through LDS (overlay), store O ----
    __syncthreads();
    float* epiO = (float*)smem;               // [widx*32+q][68] fp32
    float* epiL = (float*)(smem + 17408);     // [64]
    if (wpair == 1) {
        #pragma unroll
        for (int qt = 0; qt < 2; ++qt) {
            const int row = widx * 32 + qt * 16 + n16;
            #pragma unroll
            for (int nt = 0; nt < 4; ++nt)
                *(float4*)&epiO[row * 68 + nt * 16 + quad * 4] = (float4){
                    oacc[qt][nt][0], oacc[qt][nt][1], oacc[qt][nt][2], oacc[qt][nt][3]};
            if (quad == 0) epiL[row] = lacc[qt][0];
        }
    }
    __syncthreads();
    if (wpair == 0) {
        #pragma unroll
        for (int qt = 0; qt < 2; ++qt) {
            const int row = widx * 32 + qt * 16 + n16;
            const float inv = 1.0f / (lacc[qt][0] + epiL[row]);
            const int q = qw0 + qt * 16 + n16;
            #pragma unroll
            for (int nt = 0; nt < 4; ++nt) {
                float4 part = *(const float4*)&epiO[row * 68 + nt * 16 + quad * 4];
                float4 o;
                o.x = (oacc[qt][nt][0] + part.x) * inv;
                o.y = (oacc[qt][nt][1] + part.y) * inv;
                o.z = (oacc[qt][nt][2] + part.z) * inv;
                o.w = (oacc[qt][nt][3] + part.w) * inv;
                *(float4*)&Ob[(size_t)q * DH + nt * 16 + quad * 4] = o;
            }
        }
    }
}

// ---------------- fallback (fp32-direct) if ws too small ----------------
__global__ __launch_bounds__(256, 4)
void attn_fwd_v1(const float* __restrict__ Q, const float* __restrict__ K,
                 const float* __restrict__ V, float* __restrict__ O)
{
    __shared__ __align__(16) ushort sKf[64 * 72];
    __shared__ __align__(16) ushort sVf[64 * 72];
    __shared__ __align__(16) ushort sPf[4 * 16 * 72];
    const int bh = blockIdx.y, qt0 = blockIdx.x * 64, tid = threadIdx.x;
    const int wave = tid >> 6, lane = tid & 63, n16 = lane & 15, quad = lane >> 4;
    const size_t base = (size_t)bh * SEQ * DH;
    const float *Qb = Q + base, *Kb = K + base, *Vb = V + base;
    float* Ob = O + base;
    short8 qfrag[2];
    {
        const float* qrow = Qb + (size_t)(qt0 + wave * 16 + n16) * DH;
        #pragma unroll
        for (int t = 0; t < 2; ++t) {
            const float* p = qrow + t * 32 + quad * 8;
            short8 a;
            #pragma unroll
            for (int j = 0; j < 8; ++j) a[j] = (short)f2bf_rne(p[j] * 0.0625f);
            qfrag[t] = a;
        }
    }
    floatx4 oacc[4];
    #pragma unroll
    for (int nt = 0; nt < 4; ++nt) oacc[nt] = (floatx4){0.f,0.f,0.f,0.f};
    float m_i[4] = {-INFINITY,-INFINITY,-INFINITY,-INFINITY};
    float l_i[4] = {0.f,0.f,0.f,0.f};
    const int skr = tid >> 2, sc0 = (tid & 3) * 16;
    for (int kt0 = 0; kt0 < SEQ; kt0 += 64) {
        __syncthreads();
        const float* ksrc = Kb + (size_t)(kt0 + skr) * DH + sc0;
        const float* vsrc = Vb + (size_t)(kt0 + skr) * DH + sc0;
        ushort* kdst = &sKf[skr * 72 + sc0];
        #pragma unroll
        for (int i = 0; i < 16; i += 4) {
            float4 kf = *(const float4*)(ksrc + i);
            kdst[i+0]=f2bf_rne(kf.x); kdst[i+1]=f2bf_rne(kf.y);
            kdst[i+2]=f2bf_rne(kf.z); kdst[i+3]=f2bf_rne(kf.w);
            float4 vf = *(const float4*)(vsrc + i);
            sVf[(sc0+i+0)*72+skr]=f2bf_rne(vf.x); sVf[(sc0+i+1)*72+skr]=f2bf_rne(vf.y);
            sVf[(sc0+i+2)*72+skr]=f2bf_rne(vf.z); sVf[(sc0+i+3)*72+skr]=f2bf_rne(vf.w);
        }
        __syncthreads();
        floatx4 sacc[4];
        #pragma unroll
        for (int nt = 0; nt < 4; ++nt) {
            sacc[nt] = (floatx4){0.f,0.f,0.f,0.f};
            #pragma unroll
            for (int t = 0; t < 2; ++t) {
                short8 b = *(const short8*)&sKf[(nt*16+n16)*72 + t*32 + quad*8];
                sacc[nt] = __builtin_amdgcn_mfma_f32_16x16x32_bf16(qfrag[t], b, sacc[nt], 0,0,0);
            }
        }
        ushort* pw = &sPf[wave * 16 * 72];
        #pragma unroll
        for (int r = 0; r < 4; ++r) {
            float mx = fmaxf(fmaxf(sacc[0][r],sacc[1][r]),fmaxf(sacc[2][r],sacc[3][r]));
            #pragma unroll
            for (int off = 1; off < 16; off <<= 1) mx = fmaxf(mx, __shfl_xor(mx, off, 64));
            float mnew = fmaxf(m_i[r], mx);
            float alpha = __expf(m_i[r] - mnew);
            m_i[r] = mnew;
            float sum = 0.f;
            #pragma unroll
            for (int nt = 0; nt < 4; ++nt) {
                float p = __expf(sacc[nt][r] - mnew);
                sacc[nt][r] = p; sum += p;
            }
            #pragma unroll
            for (int off = 1; off < 16; off <<= 1) sum += __shfl_xor(sum, off, 64);
            l_i[r] = l_i[r] * alpha + sum;
            #pragma unroll
            for (int nt = 0; nt < 4; ++nt) oacc[nt][r] *= alpha;
            #pragma unroll
            for (int nt = 0; nt < 4; ++nt)
                pw[(quad*4+r)*72 + nt*16 + n16] = f2bf_rne(sacc[nt][r]);
        }
        #pragma unroll
        for (int t = 0; t < 2; ++t) {
            short8 pfr = *(const short8*)&pw[n16*72 + t*32 + quad*8];
            #pragma unroll
            for (int nt = 0; nt < 4; ++nt) {
                short8 vfr = *(const short8*)&sVf[(nt*16+n16)*72 + t*32 + quad*8];
                oacc[nt] = __builtin_amdgcn_mfma_f32_16x16x32_bf16(pfr, vfr, oacc[nt], 0,0,0);
            }
        }
    }
    #pragma unroll
    for (int r = 0; r < 4; ++r) {
        float inv = 1.0f / l_i[r];
        float* orow = Ob + (size_t)(qt0 + wave*16 + quad*4 + r) * DH;
        #pragma unroll
        for (int nt = 0; nt < 4; ++nt) orow[nt*16+n16] = oacc[nt][r] * inv;
    }
}

extern "C" void kernel_launch(void* const* d_in, const int* in_sizes, int n_in,
                              void* d_out, int out_size, void* d_ws, size_t ws_size,
                              hipStream_t stream) {
    const float* q = (const float*)d_in[0];
    const float* k = (const float*)d_in[1];
    const float* v = (const float*)d_in[2];
    float* o = (float*)d_out;
    const size_t elems = (size_t)16 * SEQ * DH;
    const size_t need  = elems * 2 * 2;     // Kf + Vf, bf16
    if (ws_size >= need) {
        ushort* kf = (ushort*)d_ws;
        ushort* vf = kf + elems;
        prep_kv<<<dim3(SEQ / 128, 16), dim3(256), 0, stream>>>(k, v, kf, vf);
        attn_fwd_v7<<<dim3(1024), dim3(256), 0, stream>>>(q, kf, vf, o);
    } else {
        attn_fwd_v1<<<dim3(SEQ / 64, 16), dim3(256), 0, stream>>>(q, k, v, o);
    }
}